// Round 1
// baseline (125.799 us; speedup 1.0000x reference)
//
#include <hip/hip_runtime.h>

// MPS tensor-train classifier, B=16384, D=784, BOND=5, OUT=10.
//
// res[b] = carry0(x0) . (prod_{m=0..781} M_m(x[m+1])) . vlast(x783)
// Round-3: SITE-PAIRING. For pair p (sites m=2p+1, 2p+2):
//   C_p = M_{2p+1} M_{2p+2} = P0 + xa*P1 + xb*P2 + xa*xb*P3
// with P0=A0A0', P1=NA0', P2=A0N', P3=NN' precomputed (prepack kernel).
// Halves matrix-chain VALU. Singles: site 0 (fwd wave) and site 781 (bwd).
// Pairs >= BWD_P0 are stored TRANSPOSED so the bwd wave uses identical
// row-vector code (v' = v @ C^T == (C v)^T).
//
// 256 blocks x 1024 thr (16 waves), lane = batch row. Wave 0: fwd vector
// chain (site 0 + pairs 0..40). Waves 1..14: 22-pair matrix products.
// Wave 15: bwd (pairs 389..349 desc + site 781). Combine via LDS (2 phases).
// pk staged through LDS double-buffer (4-pair chunks); x via v2f prefetch
// ring. Packed fp32 (ext_vector_type) for v_pk_fma_f32 selection.
//
// Round-4 (this round): __launch_bounds__(1024, 4). LDS caps us at 1
// block/CU (16 waves/CU) no matter what, so the allocator's default
// 8-waves/EU target (VGPR<=64) is pure loss: M+T+C alone need ~95 VGPRs,
// so at 64 the compiler re-reads C basis rows from LDS inside every
// matmul (lgkmcnt stalls on the FMA chain -> VALUBusy 36%). 4 waves/EU
// min -> 128 VGPR budget; steady state fits in registers.

typedef float v4f __attribute__((ext_vector_type(4)));
typedef float v2f __attribute__((ext_vector_type(2)));

constexpr int Bn     = 16384;
constexpr int Dn     = 784;
constexpr int NOUT   = 10;
constexpr int NPAIR  = 390;   // pairs cover sites 1..780
constexpr int PFV    = 41;    // fwd pairs 0..40
constexpr int PMAT   = 22;    // pairs per matrix wave (14 waves: 41..348)
constexpr int BWD_P0 = 349;   // bwd pairs 349..389 (stored transposed)
constexpr int PAIR_F = 112;   // floats per pair block: 4 mats x 28
// per-mat layout (28 floats): rows cols0-3 at 4*l (l=0..4), col4 of rows0-3
// at 20..23, element (4,4) at 24, pad 25..27.

__device__ __forceinline__ v4f splat4(float x) { v4f v = {x, x, x, x}; return v; }
__device__ __forceinline__ v4f fma4(v4f a, v4f b, v4f c) {
    return __builtin_elementwise_fma(a, b, c);
}

struct Frag { v4f r[5]; float c4[5]; };          // 5x5 running product
struct CMat { v4f row[5]; v4f c4v; float c44; }; // 5x5 pair matrix

__device__ __forceinline__ CMat build_C(const float* s, float xa, float xb) {
    CMat C;
    const float xab = xa * xb;
    const v4f va = splat4(xa), vb = splat4(xb), vab = splat4(xab);
    const v4f* s4 = (const v4f*)s;
#pragma unroll
    for (int l = 0; l < 5; ++l) {
        v4f m = s4[l];
        m = fma4(va,  s4[7 + l],  m);
        m = fma4(vb,  s4[14 + l], m);
        m = fma4(vab, s4[21 + l], m);
        C.row[l] = m;
    }
    {
        v4f m = s4[5];
        m = fma4(va,  s4[12], m);
        m = fma4(vb,  s4[19], m);
        m = fma4(vab, s4[26], m);
        C.c4v = m;
    }
    C.c44 = fmaf(xab, s[108], fmaf(xb, s[80], fmaf(xa, s[52], s[24])));
    return C;
}

// T = M @ C
__device__ __forceinline__ void matmul(const Frag& M, const CMat& C, Frag& T) {
#pragma unroll
    for (int i = 0; i < 5; ++i) {
        v4f acc  = splat4(M.r[i][0]) * C.row[0];
        float a4 = M.r[i][0] * C.c4v[0];
#pragma unroll
        for (int l = 1; l < 4; ++l) {
            acc = fma4(splat4(M.r[i][l]), C.row[l], acc);
            a4  = fmaf(M.r[i][l], C.c4v[l], a4);
        }
        acc = fma4(splat4(M.c4[i]), C.row[4], acc);
        a4  = fmaf(M.c4[i], C.c44, a4);
        T.r[i] = acc; T.c4[i] = a4;
    }
}

// c' = c @ C   (row vector)
__device__ __forceinline__ void vecstep(v4f& cv, float& c4, const CMat& C) {
    v4f acc  = splat4(cv[0]) * C.row[0];
    float a4 = cv[0] * C.c4v[0];
#pragma unroll
    for (int l = 1; l < 4; ++l) {
        acc = fma4(splat4(cv[l]), C.row[l], acc);
        a4  = fmaf(cv[l], C.c4v[l], a4);
    }
    acc = fma4(splat4(c4), C.row[4], acc);
    a4  = fmaf(c4, C.c44, a4);
    cv = acc; c4 = a4;
}

// staging: one chunk = 4 pair blocks = 112 v4f = 1792 B
__device__ __forceinline__ void sload(const v4f* src, v4f& a, v4f& b, int lane) {
    a = src[lane];
    if (lane < 48) b = src[64 + lane];
}
__device__ __forceinline__ void swrite(v4f* dst, v4f a, v4f b, int lane) {
    dst[lane] = a;
    if (lane < 48) dst[64 + lane] = b;
}

// ---- prepack: build pair blocks (transposed for p >= BWD_P0) ----
// cores_mid element (m,l,i,k) at (m*5+l)*10 + i*5 + k
__global__ void prepack_pairs(const float* __restrict__ cm, float* __restrict__ pk)
{
    int idx = blockIdx.x * 256 + threadIdx.x;
    if (idx >= NPAIR * 100) return;
    int p = idx / 100, rest = idx - p * 100;
    int q = rest / 25, e = rest - q * 25;
    int l = e / 5, r = e - l * 5;
    int m1 = 2 * p + 1, m2 = 2 * p + 2;
    const float* L = cm + (size_t)(m1 * 5 + l) * 10;
    float acc = 0.f;
#pragma unroll
    for (int k = 0; k < 5; ++k) {
        float Lk = (q & 1) ? (L[5 + k] - L[k]) : L[k];
        const float* R = cm + (size_t)(m2 * 5 + k) * 10;
        float Rk = (q & 2) ? (R[5 + r] - R[r]) : R[r];
        acc = fmaf(Lk, Rk, acc);
    }
    int wl = l, wr = r;
    if (p >= BWD_P0) { wl = r; wr = l; }   // store C^T for bwd wave
    int off = (wr < 4) ? (wl * 4 + wr) : (20 + wl);
    pk[(size_t)p * PAIR_F + q * 28 + off] = acc;
}

__global__ __launch_bounds__(1024, 4)
void mps_pair_kernel(const float* __restrict__ x,          // [B, D]
                     const float* __restrict__ core_first, // [2,5]
                     const float* __restrict__ cores_mid,  // [782,5,2,5]
                     const float* __restrict__ core_last,  // [5,2]
                     const float* __restrict__ fc_w,       // [10]
                     const float* __restrict__ fc_b,       // [10]
                     const float* __restrict__ pk,         // [390][112]
                     float* __restrict__ out)              // [B,10]
{
    __shared__ v4f   pkbuf[16][2][112];   // 57.3 KB double-buffered pair chunks
    __shared__ float matbuf[7][25][64];   // 44.8 KB combine matrices
    __shared__ float bv[5][64];           // backward vectors

    const int lane = threadIdx.x & 63;
    const int wave = threadIdx.x >> 6;
    const int row  = blockIdx.x * 64 + lane;
    const float* __restrict__ xr = x + (size_t)row * Dn;
    const v2f* __restrict__ xr2 = (const v2f*)xr;          // 392 entries
    const v4f* __restrict__ pk4 = (const v4f*)pk;

    v4f* buf0 = &pkbuf[wave][0][0];
    v4f* buf1 = &pkbuf[wave][1][0];

    if (wave >= 1 && wave <= 14) {
        // ---- matrix wave: 22 pairs, 6 chunks (5x4 + 1x2) ----
        const int w  = wave;
        const int p0 = PFV + PMAT * (w - 1);
        v4f sa, sb;
        sload(pk4 + (size_t)p0 * 28, sa, sb, lane);
        swrite(buf0, sa, sb, lane);
        sload(pk4 + (size_t)(p0 + 4) * 28, sa, sb, lane);
        v2f xc0 = xr2[p0 + 1], xc1 = xr2[p0 + 2], xc2 = xr2[p0 + 3], xc3 = xr2[p0 + 4];

        Frag M, T;
        M.r[0] = {1,0,0,0}; M.r[1] = {0,1,0,0}; M.r[2] = {0,0,1,0};
        M.r[3] = {0,0,0,1}; M.r[4] = {0,0,0,0};
        M.c4[0] = 0; M.c4[1] = 0; M.c4[2] = 0; M.c4[3] = 0; M.c4[4] = 1;

#pragma unroll 1
        for (int c = 0; c < 6; ++c) {
            v4f* wb = (c & 1) ? buf0 : buf1;
            const float* rb = (const float*)((c & 1) ? buf1 : buf0);
            swrite(wb, sa, sb, lane);                      // chunk c+1 -> LDS
            int ns = p0 + 4 * (c + 2);                     // next-next chunk
            if (ns > NPAIR - 4) ns = NPAIR - 4;
            sload(pk4 + (size_t)ns * 28, sa, sb, lane);
            const int pn = p0 + 4 * (c + 1);               // x prefetch
            v2f xn0 = xr2[pn + 1], xn1 = xr2[pn + 2], xn2 = xr2[pn + 3], xn3 = xr2[pn + 4];
            {
                CMat C = build_C(rb + 0 * PAIR_F, xc0[0], xc0[1]);
                matmul(M, C, T);
                C = build_C(rb + 1 * PAIR_F, xc1[0], xc1[1]);
                matmul(T, C, M);
            }
            if (c < 5) {
                CMat C = build_C(rb + 2 * PAIR_F, xc2[0], xc2[1]);
                matmul(M, C, T);
                C = build_C(rb + 3 * PAIR_F, xc3[0], xc3[1]);
                matmul(T, C, M);
            }
            xc0 = xn0; xc1 = xn1; xc2 = xn2; xc3 = xn3;
        }

        if (w <= 7) {
#pragma unroll
            for (int i = 0; i < 5; ++i) {
#pragma unroll
                for (int r = 0; r < 4; ++r) matbuf[w - 1][i * 5 + r][lane] = M.r[i][r];
                matbuf[w - 1][i * 5 + 4][lane] = M.c4[i];
            }
        }
        __syncthreads();   // b1
        __syncthreads();   // b2
        if (w >= 8) {
#pragma unroll
            for (int i = 0; i < 5; ++i) {
#pragma unroll
                for (int r = 0; r < 4; ++r) matbuf[w - 8][i * 5 + r][lane] = M.r[i][r];
                matbuf[w - 8][i * 5 + 4][lane] = M.c4[i];
            }
        }
        __syncthreads();   // b3
    } else if (wave == 0) {
        // ---- forward: carry0, site 0 (scalar), pairs 0..40, combine ----
        v2f x01 = xr2[0];
        float cl[5], cn[5];
#pragma unroll
        for (int r = 0; r < 5; ++r)
            cl[r] = fmaf(x01[0], core_first[5 + r] - core_first[r], core_first[r]);
        const float* cm0 = cores_mid;                      // site 0
#pragma unroll
        for (int r = 0; r < 5; ++r) {
            float a = 0.f;
#pragma unroll
            for (int l = 0; l < 5; ++l) {
                float m = fmaf(x01[1], cm0[l * 10 + 5 + r] - cm0[l * 10 + r], cm0[l * 10 + r]);
                a = fmaf(cl[l], m, a);
            }
            cn[r] = a;
        }
        v4f cv = {cn[0], cn[1], cn[2], cn[3]};
        float c4 = cn[4];

        v4f sa, sb;
        sload(pk4 + 0, sa, sb, lane);
        swrite(buf0, sa, sb, lane);
        sload(pk4 + (size_t)4 * 28, sa, sb, lane);
        v2f xc0 = xr2[1], xc1 = xr2[2], xc2 = xr2[3], xc3 = xr2[4];

#pragma unroll 1
        for (int c = 0; c < 11; ++c) {                     // 10x4 + 1x1 = 41 pairs
            v4f* wb = (c & 1) ? buf0 : buf1;
            const float* rb = (const float*)((c & 1) ? buf1 : buf0);
            swrite(wb, sa, sb, lane);
            int ns = 4 * (c + 2);
            if (ns > NPAIR - 4) ns = NPAIR - 4;
            sload(pk4 + (size_t)ns * 28, sa, sb, lane);
            const int pn = 4 * (c + 1);
            v2f xn0 = xr2[pn + 1], xn1 = xr2[pn + 2], xn2 = xr2[pn + 3], xn3 = xr2[pn + 4];
            {
                CMat C = build_C(rb + 0 * PAIR_F, xc0[0], xc0[1]);
                vecstep(cv, c4, C);
            }
            if (c < 10) {
                CMat C = build_C(rb + 1 * PAIR_F, xc1[0], xc1[1]);
                vecstep(cv, c4, C);
                C = build_C(rb + 2 * PAIR_F, xc2[0], xc2[1]);
                vecstep(cv, c4, C);
                C = build_C(rb + 3 * PAIR_F, xc3[0], xc3[1]);
                vecstep(cv, c4, C);
            }
            xc0 = xn0; xc1 = xn1; xc2 = xn2; xc3 = xn3;
        }
        cl[0] = cv[0]; cl[1] = cv[1]; cl[2] = cv[2]; cl[3] = cv[3]; cl[4] = c4;

        __syncthreads();   // b1: phase-1 matrices ready
#pragma unroll 1
        for (int w2 = 0; w2 < 7; ++w2) {
            float v0[5];
#pragma unroll
            for (int r = 0; r < 5; ++r) v0[r] = cl[0] * matbuf[w2][r][lane];
#pragma unroll
            for (int l = 1; l < 5; ++l)
#pragma unroll
                for (int r = 0; r < 5; ++r)
                    v0[r] = fmaf(cl[l], matbuf[w2][l * 5 + r][lane], v0[r]);
#pragma unroll
            for (int r = 0; r < 5; ++r) cl[r] = v0[r];
        }
        __syncthreads();   // b2
        __syncthreads();   // b3: phase-2 matrices + bv ready
#pragma unroll 1
        for (int w2 = 0; w2 < 7; ++w2) {
            float v0[5];
#pragma unroll
            for (int r = 0; r < 5; ++r) v0[r] = cl[0] * matbuf[w2][r][lane];
#pragma unroll
            for (int l = 1; l < 5; ++l)
#pragma unroll
                for (int r = 0; r < 5; ++r)
                    v0[r] = fmaf(cl[l], matbuf[w2][l * 5 + r][lane], v0[r]);
#pragma unroll
            for (int r = 0; r < 5; ++r) cl[r] = v0[r];
        }
        float res = 0.f;
#pragma unroll
        for (int l = 0; l < 5; ++l) res = fmaf(cl[l], bv[l][lane], res);
        float* orow = out + (size_t)row * NOUT;
#pragma unroll
        for (int o = 0; o < NOUT; ++o) orow[o] = fmaf(res, fc_w[o], fc_b[o]);
    } else {
        // ---- backward: vlast, site 781 (scalar), pairs 389..349 desc ----
        v2f xz = xr2[391];                                 // {x782, x783}
        float vl[5], vn[5];
#pragma unroll
        for (int l = 0; l < 5; ++l)
            vl[l] = fmaf(xz[1], core_last[2 * l + 1] - core_last[2 * l], core_last[2 * l]);
        const float* cmL = cores_mid + (size_t)781 * 50;
#pragma unroll
        for (int l = 0; l < 5; ++l) {
            float a = 0.f;
#pragma unroll
            for (int r = 0; r < 5; ++r) {
                float m = fmaf(xz[0], cmL[l * 10 + 5 + r] - cmL[l * 10 + r], cmL[l * 10 + r]);
                a = fmaf(m, vl[r], a);
            }
            vn[l] = a;
        }
        v4f cv = {vn[0], vn[1], vn[2], vn[3]};
        float c4 = vn[4];

        v4f sa, sb;
        sload(pk4 + (size_t)386 * 28, sa, sb, lane);       // chunk0: pairs 386..389
        swrite(buf0, sa, sb, lane);
        sload(pk4 + (size_t)382 * 28, sa, sb, lane);
        v2f xc0 = xr2[390], xc1 = xr2[389], xc2 = xr2[388], xc3 = xr2[387];

#pragma unroll 1
        for (int c = 0; c < 11; ++c) {                     // 10x4 + 1x1 = 41 pairs
            v4f* wb = (c & 1) ? buf0 : buf1;
            const float* rb = (const float*)((c & 1) ? buf1 : buf0);
            swrite(wb, sa, sb, lane);
            int ns = 386 - 4 * (c + 2);                    // >= 338, in bounds
            sload(pk4 + (size_t)ns * 28, sa, sb, lane);
            const int bn = 386 - 4 * (c + 1);
            v2f xn0 = xr2[bn + 4], xn1 = xr2[bn + 3], xn2 = xr2[bn + 2], xn3 = xr2[bn + 1];
            {
                CMat C = build_C(rb + 3 * PAIR_F, xc0[0], xc0[1]);  // highest pair first
                vecstep(cv, c4, C);
            }
            if (c < 10) {
                CMat C = build_C(rb + 2 * PAIR_F, xc1[0], xc1[1]);
                vecstep(cv, c4, C);
                C = build_C(rb + 1 * PAIR_F, xc2[0], xc2[1]);
                vecstep(cv, c4, C);
                C = build_C(rb + 0 * PAIR_F, xc3[0], xc3[1]);
                vecstep(cv, c4, C);
            }
            xc0 = xn0; xc1 = xn1; xc2 = xn2; xc3 = xn3;
        }

        __syncthreads();   // b1
        __syncthreads();   // b2
        bv[0][lane] = cv[0]; bv[1][lane] = cv[1]; bv[2][lane] = cv[2];
        bv[3][lane] = cv[3]; bv[4][lane] = c4;
        __syncthreads();   // b3
    }
}

extern "C" void kernel_launch(void* const* d_in, const int* in_sizes, int n_in,
                              void* d_out, int out_size, void* d_ws, size_t ws_size,
                              hipStream_t stream) {
    const float* x          = (const float*)d_in[0];
    const float* core_first = (const float*)d_in[1];
    const float* cores_mid  = (const float*)d_in[2];
    const float* core_last  = (const float*)d_in[3];
    const float* fc_w       = (const float*)d_in[4];
    const float* fc_b       = (const float*)d_in[5];
    float* out              = (float*)d_out;
    float* pk               = (float*)d_ws;   // 390*112*4 = 174,720 B

    hipLaunchKernelGGL(prepack_pairs, dim3((NPAIR * 100 + 255) / 256), dim3(256),
                       0, stream, cores_mid, pk);
    hipLaunchKernelGGL(mps_pair_kernel, dim3(Bn / 64), dim3(1024), 0, stream,
                       x, core_first, cores_mid, core_last, fc_w, fc_b, pk, out);
}